// Round 13
// baseline (427.332 us; speedup 1.0000x reference)
//
#include <hip/hip_runtime.h>
#include <hip/hip_fp16.h>
#include <math.h>

#define HEADS 4
#define HDIM 32
#define FD 128
#define NEG 0.2f
#define BCAP 4608    // per bucket (128 dsts) capacity (lambda=4092, +8 sigma)
#define CH 8192      // edges per binning chunk
#define CHW 128      // edges per aggr chunk (per wave)

typedef _Float16 f16x8 __attribute__((ext_vector_type(8)));
typedef float f32x4 __attribute__((ext_vector_type(4)));

__device__ __forceinline__ float lrelu(float x) { return fmaxf(x, NEG * x); }

// ---- fused prep: x0 cvt (blocks 0..ncvt-1), W16T+va (ncvt..ncvt+2),
//      bcnt zero (ncvt+3) ----
__global__ __launch_bounds__(256) void k_prep(const float* __restrict__ x,
                                              __half* __restrict__ o, long nF,
                                              const float* __restrict__ W,
                                              const float* __restrict__ att_s,
                                              const float* __restrict__ att_d,
                                              _Float16* __restrict__ W16T,
                                              float* __restrict__ va_s,
                                              float* __restrict__ va_d,
                                              int* __restrict__ bcnt, int nbuck,
                                              int ncvt) {
    int b = blockIdx.x;
    if (b < ncvt) {
        long i = ((long)b * 256 + threadIdx.x) * 4;
        if (i < nF) {
            float4 v = *(const float4*)&x[i];
            *(__half2*)&o[i] = __floats2half2_rn(v.x, v.y);
            *(__half2*)&o[i + 2] = __floats2half2_rn(v.z, v.w);
        }
        return;
    }
    if (b == ncvt + 3) {
        for (int i = threadIdx.x; i < nbuck; i += 256) bcnt[i] = 0;
        return;
    }
    int l = b - ncvt;
    const float* Wl = W + (long)l * FD * FD;
    _Float16* ow = W16T + (long)l * FD * FD;
    for (int i = threadIdx.x; i < FD * FD; i += 256) {
        int k = i >> 7, n = i & 127;
        ow[n * FD + k] = (_Float16)Wl[i];
    }
    const float* as_l = att_s + l * HEADS * HDIM;
    const float* ad_l = att_d + l * HEADS * HDIM;
    for (int idx = threadIdx.x; idx < HEADS * FD; idx += 256) {
        int hd = idx >> 7, k = idx & 127;
        float ss = 0.f, dd = 0.f;
        for (int c = 0; c < HDIM; ++c) {
            float w = Wl[k * FD + hd * HDIM + c];
            ss += w * as_l[hd * HDIM + c];
            dd += w * ad_l[hd * HDIM + c];
        }
        va_s[(long)l * HEADS * FD + idx] = ss;
        va_d[(long)l * HEADS * FD + idx] = dd;
    }
}

// ---- MFMA GEMM: h = x16 @ W (fp16 in, fp16 out, fp32 accum) ----
__global__ __launch_bounds__(256) void k_gemm_mfma(const __half* __restrict__ x16,
                                                   const _Float16* __restrict__ W16T,
                                                   __half* __restrict__ h, int N) {
    __shared__ _Float16 wl[FD * FD];  // 32 KB, [n][k]
    int t = threadIdx.x;
    for (int i = t * 8; i < FD * FD; i += 2048)
        *(f16x8*)&wl[i] = *(const f16x8*)&W16T[i];

    int w = t >> 6, lane = t & 63;
    int m = lane & 15, quad = lane >> 4;
    int row0 = blockIdx.x * 128 + w * 32;

    f16x8 a[2][4];
    f16x8 zf = {};
#pragma unroll
    for (int rt = 0; rt < 2; ++rt) {
        int gr = row0 + rt * 16 + m;
#pragma unroll
        for (int kc = 0; kc < 4; ++kc)
            a[rt][kc] = (gr < N) ? *(const f16x8*)&x16[(long)gr * FD + kc * 32 + quad * 8] : zf;
    }
    f32x4 acc[2][8];
#pragma unroll
    for (int rt = 0; rt < 2; ++rt)
#pragma unroll
        for (int c = 0; c < 8; ++c) acc[rt][c] = (f32x4){0.f, 0.f, 0.f, 0.f};

    __syncthreads();
#pragma unroll
    for (int c = 0; c < 8; ++c) {
        int nb = c * 16 + m;
#pragma unroll
        for (int kc = 0; kc < 4; ++kc) {
            f16x8 b = *(f16x8*)&wl[nb * FD + kc * 32 + quad * 8];
            acc[0][c] = __builtin_amdgcn_mfma_f32_16x16x32_f16(a[0][kc], b, acc[0][c], 0, 0, 0);
            acc[1][c] = __builtin_amdgcn_mfma_f32_16x16x32_f16(a[1][kc], b, acc[1][c], 0, 0, 0);
        }
    }
#pragma unroll
    for (int rt = 0; rt < 2; ++rt) {
        int rbase = row0 + rt * 16 + quad * 4;
#pragma unroll
        for (int c = 0; c < 8; ++c) {
            int col = c * 16 + m;
#pragma unroll
            for (int i = 0; i < 4; ++i) {
                int gr = rbase + i;
                if (gr < N) h[(long)gr * FD + col] = __float2half(acc[rt][c][i]);
            }
        }
    }
}

// ---- attention halves for layer 0 (from h): 16 threads/node ----
__global__ __launch_bounds__(256) void k_alpha(const __half* __restrict__ h,
                                               const float* __restrict__ a_s,
                                               const float* __restrict__ a_d,
                                               float* __restrict__ as_o,
                                               float* __restrict__ ad_o, int N) {
    int t = threadIdx.x;
    int n = blockIdx.x * 16 + (t >> 4);
    if (n >= N) return;
    int c16 = t & 15, gh = c16 >> 2, cb = c16 * 8;
    int c32 = (c16 & 3) * 8;
    float4 raw = *(const float4*)&h[(long)n * FD + cb];
    const __half* hh = (const __half*)&raw;
    float vs = 0.f, vd = 0.f;
#pragma unroll
    for (int i = 0; i < 8; ++i) {
        float hv = __half2float(hh[i]);
        vs += hv * a_s[gh * HDIM + c32 + i];
        vd += hv * a_d[gh * HDIM + c32 + i];
    }
    vs += __shfl_xor(vs, 1); vs += __shfl_xor(vs, 2);
    vd += __shfl_xor(vd, 1); vd += __shfl_xor(vd, 2);
    if ((c16 & 3) == 0) {
        as_o[n * HEADS + gh] = vs;
        ad_o[n * HEADS + gh] = vd;
    }
}

// ---- Pass A: chunk-reserved binning ----
__global__ __launch_bounds__(1024) void k_bin(const int* __restrict__ ei, int NE,
                                              int nbuck,
                                              int* __restrict__ bcnt,
                                              int* __restrict__ binned) {
    __shared__ int hist[512];
    __shared__ int gbase[512];
    int t = threadIdx.x;
    int c0 = blockIdx.x * CH;
    if (t < 512) hist[t] = 0;
    __syncthreads();
    int sub[8], val[8], loff[8];
#pragma unroll
    for (int k = 0; k < 8; ++k) {
        int idx = c0 + k * 1024 + t;
        sub[k] = -1;
        if (idx < NE) {
            int s = ei[idx], d = ei[NE + idx];
            sub[k] = d >> 7;
            val[k] = s | ((d & 127) << 16);   // requires N < 65536
            loff[k] = atomicAdd(&hist[sub[k]], 1);
        }
    }
    __syncthreads();
    if (t < 512 && t < nbuck && hist[t] > 0)
        gbase[t] = atomicAdd(&bcnt[t], hist[t]);
    __syncthreads();
#pragma unroll
    for (int k = 0; k < 8; ++k) {
        if (sub[k] >= 0) {
            int p = gbase[sub[k]] + loff[k];
            if (p < BCAP) binned[(long)sub[k] * BCAP + p] = val[k];
        }
    }
}

// scan of bcnt -> bbase; also rowstart[N]=NE, cnt[0..G)=0, out zeroing
__global__ __launch_bounds__(1024) void k_scan_sub(const int* __restrict__ bcnt,
                                                   int* __restrict__ bbase, int n,
                                                   int* __restrict__ rowstart, int N, int NE,
                                                   float* __restrict__ cnt, int G,
                                                   float* __restrict__ outz) {
    __shared__ int sm[1024];
    int t = threadIdx.x;
    int c0 = t * 4;
    int v0 = (c0 < n) ? bcnt[c0] : 0;
    int v1 = (c0 + 1 < n) ? bcnt[c0 + 1] : 0;
    int v2 = (c0 + 2 < n) ? bcnt[c0 + 2] : 0;
    int v3 = (c0 + 3 < n) ? bcnt[c0 + 3] : 0;
    int tot = v0 + v1 + v2 + v3;
    sm[t] = tot;
    if (t < G) cnt[t] = 0.f;
    __syncthreads();
    for (int off = 1; off < 1024; off <<= 1) {
        int u = (t >= off) ? sm[t - off] : 0;
        __syncthreads();
        sm[t] += u;
        __syncthreads();
    }
    int base = sm[t] - tot;
    if (c0 < n) bbase[c0] = base;
    if (c0 + 1 < n) bbase[c0 + 1] = base + v0;
    if (c0 + 2 < n) bbase[c0 + 2] = base + v0 + v1;
    if (c0 + 3 < n) bbase[c0 + 3] = base + v0 + v1 + v2;
    if (t == 1023) {
        bbase[n] = sm[1023];
        rowstart[N] = NE;
    }
    long tot_out = (long)G * FD;
    for (long i = t * 4; i < tot_out; i += 4096)
        *(float4*)&outz[i] = (float4){0.f, 0.f, 0.f, 0.f};
}

__global__ __launch_bounds__(256) void k_bucket_csr(const int* __restrict__ binned,
                                                    const int* __restrict__ bcnt,
                                                    const int* __restrict__ bbase,
                                                    int* __restrict__ csr_src,
                                                    int* __restrict__ rowstart, int N) {
    int b = blockIdx.x;
    int t = threadIdx.x;
    __shared__ int ldeg[128], lofs[128], lcur[128];
    __shared__ int lcsr[BCAP];
    if (t < 128) ldeg[t] = 0;
    __syncthreads();
    int cnt = bcnt[b];
    if (cnt > BCAP) cnt = BCAP;
    int base = bbase[b];
    const int* reg = binned + (long)b * BCAP;
    for (int i = t; i < cnt; i += 256)
        atomicAdd(&ldeg[reg[i] >> 16], 1);
    __syncthreads();
    if (t < 128) lofs[t] = ldeg[t];
    __syncthreads();
    for (int off = 1; off < 128; off <<= 1) {
        int u = (t < 128 && t >= off) ? lofs[t - off] : 0;
        __syncthreads();
        if (t < 128) lofs[t] += u;
        __syncthreads();
    }
    if (t < 128) lcur[t] = lofs[t] - ldeg[t];
    __syncthreads();
    for (int i = t; i < cnt; i += 256) {
        int v = reg[i];
        int p = atomicAdd(&lcur[v >> 16], 1);
        lcsr[p] = v & 0xFFFF;
    }
    __syncthreads();
    for (int i = t; i < cnt; i += 256) csr_src[base + i] = lcsr[i];
    if (t < 128) {
        int d = b * 128 + t;
        if (d < N) rowstart[d] = base + lofs[t] - ldeg[t];
    }
}

// ---- wave-per-node aggregation, 8 edge-groups x 8 lanes x 16 ch ----
// Inline weights (R11 style); wider channel footprint halves per-edge
// amortized overhead (s_lds read, as_ gather, exp chain, h addressing).
__global__ __launch_bounds__(256) void k_aggr(const int* __restrict__ csr_src,
                                              const int* __restrict__ rowstart,
                                              const float* __restrict__ as_,
                                              const float* __restrict__ ad_,
                                              const __half* __restrict__ h,
                                              const float* __restrict__ bias,
                                              const float* __restrict__ va_s,
                                              const float* __restrict__ va_d,
                                              float* __restrict__ as_n,
                                              float* __restrict__ ad_n,
                                              __half* __restrict__ out, int N) {
    __shared__ int s_all[4][CHW];
    int t = threadIdx.x;
    int wv = t >> 6, lane = t & 63;
    int n = blockIdx.x * 4 + wv;
    if (n >= N) return;
    int* s_lds = s_all[wv];
    int c8 = lane & 7, rg = lane >> 3;
    int gh = c8 >> 1;
    int cb = c8 * 16;
    int beg = rowstart[n], end = rowstart[n + 1];
    int deg = end - beg;
    float adn = ad_[n * HEADS + gh];
    float l = 0.f;
    float acc[16];
#pragma unroll
    for (int i = 0; i < 16; ++i) acc[i] = 0.f;

    for (int c0 = 0; c0 < deg; c0 += CHW) {
        int cnt = deg - c0;
        if (cnt > CHW) cnt = CHW;
        for (int i = lane; i < cnt; i += 64) s_lds[i] = csr_src[beg + c0 + i];
        __builtin_amdgcn_wave_barrier();  // keep compiler from reordering LDS ops
#pragma unroll 2
        for (int e = rg; e < cnt; e += 8) {
            int s = s_lds[e];
            float lg = lrelu(as_[s * HEADS + gh] + adn);
            float w = __expf(fminf(lg, 30.f));
            l += w;
            const __half* hp = &h[(long)s * FD + cb];
            float4 r0 = *(const float4*)hp;
            float4 r1 = *(const float4*)(hp + 8);
            const __half* h0 = (const __half*)&r0;
            const __half* h1 = (const __half*)&r1;
#pragma unroll
            for (int i = 0; i < 8; ++i) {
                acc[i] += __half2float(h0[i]) * w;      // v_fma_mix_f32
                acc[8 + i] += __half2float(h1[i]) * w;
            }
        }
        __builtin_amdgcn_wave_barrier();
    }
    // reduce over the 8 edge-groups (lane bits 3..5)
    l += __shfl_xor(l, 8);
    l += __shfl_xor(l, 16);
    l += __shfl_xor(l, 32);
#pragma unroll
    for (int i = 0; i < 16; ++i) {
        acc[i] += __shfl_xor(acc[i], 8);
        acc[i] += __shfl_xor(acc[i], 16);
        acc[i] += __shfl_xor(acc[i], 32);
    }
    float sl = lrelu(as_[n * HEADS + gh] + adn);
    float sw = __expf(fminf(sl, 30.f));
    float inv = 1.f / (l + sw + 1e-16f);
    const __half* hn = &h[(long)n * FD + cb];
    float4 rh0 = *(const float4*)hn;
    float4 rh1 = *(const float4*)(hn + 8);
    const __half* hh0 = (const __half*)&rh0;
    const __half* hh1 = (const __half*)&rh1;
    float4 b0 = *(const float4*)&bias[cb];
    float4 b1 = *(const float4*)&bias[cb + 4];
    float4 b2 = *(const float4*)&bias[cb + 8];
    float4 b3 = *(const float4*)&bias[cb + 12];
    float bb[16] = {b0.x, b0.y, b0.z, b0.w, b1.x, b1.y, b1.z, b1.w,
                    b2.x, b2.y, b2.z, b2.w, b3.x, b3.y, b3.z, b3.w};
    float v[16];
#pragma unroll
    for (int i = 0; i < 8; ++i) {
        float u0 = (acc[i] + sw * __half2float(hh0[i])) * inv + bb[i];
        v[i] = u0 > 0.f ? u0 : expm1f(u0);
        float u1 = (acc[8 + i] + sw * __half2float(hh1[i])) * inv + bb[8 + i];
        v[8 + i] = u1 > 0.f ? u1 : expm1f(u1);
    }
    if (rg == 0) {
        __half o16[16];
#pragma unroll
        for (int i = 0; i < 16; ++i) o16[i] = __float2half(v[i]);
        *(float4*)&out[(long)n * FD + cb] = ((float4*)o16)[0];
        *(float4*)&out[(long)n * FD + cb + 8] = ((float4*)o16)[1];
    }
    if (va_s) {  // next-layer alpha halves: hd = rg&3, dot over all 128 ch
        int hd = rg & 3;
        const float* vsp = va_s + hd * FD + cb;
        const float* vdp = va_d + hd * FD + cb;
        float ps = 0.f, pd = 0.f;
#pragma unroll
        for (int i = 0; i < 16; ++i) {
            ps += v[i] * vsp[i];
            pd += v[i] * vdp[i];
        }
        ps += __shfl_xor(ps, 1); ps += __shfl_xor(ps, 2); ps += __shfl_xor(ps, 4);
        pd += __shfl_xor(pd, 1); pd += __shfl_xor(pd, 2); pd += __shfl_xor(pd, 4);
        if (c8 == 0 && rg < 4) {
            as_n[n * HEADS + hd] = ps;
            ad_n[n * HEADS + hd] = pd;
        }
    }
}

// ---- pooling: batch sorted -> segmented accumulate (32 nodes/block) ----
__global__ __launch_bounds__(128) void k_pool(const __half* __restrict__ x,
                                              const int* __restrict__ batch,
                                              float* __restrict__ out,
                                              float* __restrict__ cnt, int N) {
    int n0 = blockIdx.x * 32;
    if (n0 >= N) return;
    int n1 = n0 + 32;
    if (n1 > N) n1 = N;
    int ch = threadIdx.x;
    __shared__ int gb[32];
    if (ch < n1 - n0) gb[ch] = batch[n0 + ch];
    __syncthreads();
    int g = gb[0];
    float sum = 0.f, c_local = 0.f;
    for (int n = n0; n < n1; ++n) {
        int gn = gb[n - n0];
        if (gn != g) {
            atomicAdd(&out[(long)g * FD + ch], sum);
            if (ch == 0) atomicAdd(&cnt[g], c_local);
            sum = 0.f;
            c_local = 0.f;
            g = gn;
        }
        sum += __half2float(x[(long)n * FD + ch]);
        c_local += 1.f;
    }
    atomicAdd(&out[(long)g * FD + ch], sum);
    if (ch == 0) atomicAdd(&cnt[g], c_local);
}

__global__ void k_div(float* __restrict__ out, const float* __restrict__ cnt, int G) {
    int i = blockIdx.x * 256 + threadIdx.x;
    if (i >= G * FD) return;
    float c = cnt[i >> 7];
    out[i] /= (c > 1.f ? c : 1.f);
}

extern "C" void kernel_launch(void* const* d_in, const int* in_sizes, int n_in,
                              void* d_out, int out_size, void* d_ws, size_t ws_size,
                              hipStream_t stream) {
    const float* x0     = (const float*)d_in[0];
    const float* Wall   = (const float*)d_in[1];
    const float* att_s  = (const float*)d_in[2];
    const float* att_d  = (const float*)d_in[3];
    const float* biases = (const float*)d_in[4];
    const int*   ei     = (const int*)d_in[5];
    const int*   batch  = (const int*)d_in[6];
    float*       out    = (float*)d_out;

    int N  = in_sizes[0] / FD;   // 50000 (src packing relies on N < 65536)
    int NE = in_sizes[5] / 2;    // 1600000
    int G  = out_size / FD;      // 512

    int nbuck = (N + 127) >> 7;  // 391

    long nF = (long)N * FD;
    float*    wsf      = (float*)d_ws;
    float*    asA      = wsf;                        // 4N
    float*    adA      = asA + (long)N * HEADS;      // 4N
    float*    asB      = adA + (long)N * HEADS;      // 4N
    float*    adB      = asB + (long)N * HEADS;      // 4N
    float*    cnt      = adB + (long)N * HEADS;      // G
    float*    va_s     = cnt + G;                    // 3*4*FD
    float*    va_d     = va_s + 3 * HEADS * FD;      // 3*4*FD
    int*      rowstart = (int*)(va_d + 3 * HEADS * FD); // N+1
    int*      bcnt     = rowstart + N + 1;           // nbuck
    int*      bbase    = bcnt + nbuck;               // nbuck+1
    int*      csr_src  = bbase + nbuck + 1;          // NE
    __half*   h        = (__half*)(csr_src + NE);    // nF halves
    __half*   x16      = h + nF;                     // nF halves
    _Float16* W16T     = (_Float16*)(x16 + nF);      // 3*FD*FD halves
    int*      binned   = (int*)(W16T + 3 * FD * FD); // nbuck*BCAP ints

    int ncvt = (int)((nF / 4 + 255) / 256);

    // ---- prep (cvt + W prep + bcnt zero) + CSR build ----
    k_prep<<<ncvt + 4, 256, 0, stream>>>(x0, x16, nF, Wall, att_s, att_d,
                                         W16T, va_s, va_d, bcnt, nbuck, ncvt);
    k_bin<<<(NE + CH - 1) / CH, 1024, 0, stream>>>(ei, NE, nbuck, bcnt, binned);
    k_scan_sub<<<1, 1024, 0, stream>>>(bcnt, bbase, nbuck, rowstart, N, NE, cnt, G, out);
    k_bucket_csr<<<nbuck, 256, 0, stream>>>(binned, bcnt, bbase, csr_src, rowstart, N);

    // ---- layers (alpha for layer 0 standalone; layers 1,2 from aggr epilogue) ----
    float* asR[3] = {asA, asB, asA};
    float* adR[3] = {adA, adB, adA};
    for (int l = 0; l < 3; ++l) {
        k_gemm_mfma<<<(N + 127) / 128, 256, 0, stream>>>(x16, W16T + (long)l * FD * FD, h, N);
        if (l == 0)
            k_alpha<<<(N + 15) / 16, 256, 0, stream>>>(h, att_s, att_d, asA, adA, N);
        const float* vs = (l < 2) ? va_s + (long)(l + 1) * HEADS * FD : nullptr;
        const float* vd = (l < 2) ? va_d + (long)(l + 1) * HEADS * FD : nullptr;
        k_aggr<<<(N + 3) / 4, 256, 0, stream>>>(csr_src, rowstart, asR[l], adR[l], h,
                                                biases + l * FD, vs, vd,
                                                asR[l + 1 < 3 ? l + 1 : 0],
                                                adR[l + 1 < 3 ? l + 1 : 0], x16, N);
    }

    // ---- pooling ----
    k_pool<<<(N + 31) / 32, 128, 0, stream>>>(x16, batch, out, cnt, N);
    k_div<<<(G * FD + 255) / 256, 256, 0, stream>>>(out, cnt, G);
}

// Round 14
// 390.570 us; speedup vs baseline: 1.0941x; 1.0941x over previous
//
#include <hip/hip_runtime.h>
#include <hip/hip_fp16.h>
#include <math.h>

#define HEADS 4
#define HDIM 32
#define FD 128
#define NEG 0.2f
#define BCAP 4608    // per bucket (128 dsts) capacity (lambda=4092, +8 sigma)
#define CH 8192      // edges per binning chunk
#define CHW 128      // edges per aggr chunk (per wave)

typedef _Float16 f16x8 __attribute__((ext_vector_type(8)));
typedef float f32x4 __attribute__((ext_vector_type(4)));

__device__ __forceinline__ float lrelu(float x) { return fmaxf(x, NEG * x); }

// ---- fused prep: x0 cvt (blocks 0..ncvt-1), W16T+va (ncvt..ncvt+2),
//      bcnt zero (ncvt+3) ----
__global__ __launch_bounds__(256) void k_prep(const float* __restrict__ x,
                                              __half* __restrict__ o, long nF,
                                              const float* __restrict__ W,
                                              const float* __restrict__ att_s,
                                              const float* __restrict__ att_d,
                                              _Float16* __restrict__ W16T,
                                              float* __restrict__ va_s,
                                              float* __restrict__ va_d,
                                              int* __restrict__ bcnt, int nbuck,
                                              int ncvt) {
    int b = blockIdx.x;
    if (b < ncvt) {
        long i = ((long)b * 256 + threadIdx.x) * 4;
        if (i < nF) {
            float4 v = *(const float4*)&x[i];
            *(__half2*)&o[i] = __floats2half2_rn(v.x, v.y);
            *(__half2*)&o[i + 2] = __floats2half2_rn(v.z, v.w);
        }
        return;
    }
    if (b == ncvt + 3) {
        for (int i = threadIdx.x; i < nbuck; i += 256) bcnt[i] = 0;
        return;
    }
    int l = b - ncvt;
    const float* Wl = W + (long)l * FD * FD;
    _Float16* ow = W16T + (long)l * FD * FD;
    for (int i = threadIdx.x; i < FD * FD; i += 256) {
        int k = i >> 7, n = i & 127;
        ow[n * FD + k] = (_Float16)Wl[i];
    }
    const float* as_l = att_s + l * HEADS * HDIM;
    const float* ad_l = att_d + l * HEADS * HDIM;
    for (int idx = threadIdx.x; idx < HEADS * FD; idx += 256) {
        int hd = idx >> 7, k = idx & 127;
        float ss = 0.f, dd = 0.f;
        for (int c = 0; c < HDIM; ++c) {
            float w = Wl[k * FD + hd * HDIM + c];
            ss += w * as_l[hd * HDIM + c];
            dd += w * ad_l[hd * HDIM + c];
        }
        va_s[(long)l * HEADS * FD + idx] = ss;
        va_d[(long)l * HEADS * FD + idx] = dd;
    }
}

// ---- MFMA GEMM: h = x16 @ W (fp16 in, fp16 out, fp32 accum) ----
__global__ __launch_bounds__(256) void k_gemm_mfma(const __half* __restrict__ x16,
                                                   const _Float16* __restrict__ W16T,
                                                   __half* __restrict__ h, int N) {
    __shared__ _Float16 wl[FD * FD];  // 32 KB, [n][k]
    int t = threadIdx.x;
    for (int i = t * 8; i < FD * FD; i += 2048)
        *(f16x8*)&wl[i] = *(const f16x8*)&W16T[i];

    int w = t >> 6, lane = t & 63;
    int m = lane & 15, quad = lane >> 4;
    int row0 = blockIdx.x * 128 + w * 32;

    f16x8 a[2][4];
    f16x8 zf = {};
#pragma unroll
    for (int rt = 0; rt < 2; ++rt) {
        int gr = row0 + rt * 16 + m;
#pragma unroll
        for (int kc = 0; kc < 4; ++kc)
            a[rt][kc] = (gr < N) ? *(const f16x8*)&x16[(long)gr * FD + kc * 32 + quad * 8] : zf;
    }
    f32x4 acc[2][8];
#pragma unroll
    for (int rt = 0; rt < 2; ++rt)
#pragma unroll
        for (int c = 0; c < 8; ++c) acc[rt][c] = (f32x4){0.f, 0.f, 0.f, 0.f};

    __syncthreads();
#pragma unroll
    for (int c = 0; c < 8; ++c) {
        int nb = c * 16 + m;
#pragma unroll
        for (int kc = 0; kc < 4; ++kc) {
            f16x8 b = *(f16x8*)&wl[nb * FD + kc * 32 + quad * 8];
            acc[0][c] = __builtin_amdgcn_mfma_f32_16x16x32_f16(a[0][kc], b, acc[0][c], 0, 0, 0);
            acc[1][c] = __builtin_amdgcn_mfma_f32_16x16x32_f16(a[1][kc], b, acc[1][c], 0, 0, 0);
        }
    }
#pragma unroll
    for (int rt = 0; rt < 2; ++rt) {
        int rbase = row0 + rt * 16 + quad * 4;
#pragma unroll
        for (int c = 0; c < 8; ++c) {
            int col = c * 16 + m;
#pragma unroll
            for (int i = 0; i < 4; ++i) {
                int gr = rbase + i;
                if (gr < N) h[(long)gr * FD + col] = __float2half(acc[rt][c][i]);
            }
        }
    }
}

// ---- attention halves for layer 0 (from h): 16 threads/node ----
__global__ __launch_bounds__(256) void k_alpha(const __half* __restrict__ h,
                                               const float* __restrict__ a_s,
                                               const float* __restrict__ a_d,
                                               float* __restrict__ as_o,
                                               float* __restrict__ ad_o, int N) {
    int t = threadIdx.x;
    int n = blockIdx.x * 16 + (t >> 4);
    if (n >= N) return;
    int c16 = t & 15, gh = c16 >> 2, cb = c16 * 8;
    int c32 = (c16 & 3) * 8;
    float4 raw = *(const float4*)&h[(long)n * FD + cb];
    const __half* hh = (const __half*)&raw;
    float vs = 0.f, vd = 0.f;
#pragma unroll
    for (int i = 0; i < 8; ++i) {
        float hv = __half2float(hh[i]);
        vs += hv * a_s[gh * HDIM + c32 + i];
        vd += hv * a_d[gh * HDIM + c32 + i];
    }
    vs += __shfl_xor(vs, 1); vs += __shfl_xor(vs, 2);
    vd += __shfl_xor(vd, 1); vd += __shfl_xor(vd, 2);
    if ((c16 & 3) == 0) {
        as_o[n * HEADS + gh] = vs;
        ad_o[n * HEADS + gh] = vd;
    }
}

// ---- Pass A: chunk-reserved binning ----
__global__ __launch_bounds__(1024) void k_bin(const int* __restrict__ ei, int NE,
                                              int nbuck,
                                              int* __restrict__ bcnt,
                                              int* __restrict__ binned) {
    __shared__ int hist[512];
    __shared__ int gbase[512];
    int t = threadIdx.x;
    int c0 = blockIdx.x * CH;
    if (t < 512) hist[t] = 0;
    __syncthreads();
    int sub[8], val[8], loff[8];
#pragma unroll
    for (int k = 0; k < 8; ++k) {
        int idx = c0 + k * 1024 + t;
        sub[k] = -1;
        if (idx < NE) {
            int s = ei[idx], d = ei[NE + idx];
            sub[k] = d >> 7;
            val[k] = s | ((d & 127) << 16);   // requires N < 65536
            loff[k] = atomicAdd(&hist[sub[k]], 1);
        }
    }
    __syncthreads();
    if (t < 512 && t < nbuck && hist[t] > 0)
        gbase[t] = atomicAdd(&bcnt[t], hist[t]);
    __syncthreads();
#pragma unroll
    for (int k = 0; k < 8; ++k) {
        if (sub[k] >= 0) {
            int p = gbase[sub[k]] + loff[k];
            if (p < BCAP) binned[(long)sub[k] * BCAP + p] = val[k];
        }
    }
}

// scan of bcnt -> bbase; also rowstart[N]=NE, cnt[0..G)=0, out zeroing
__global__ __launch_bounds__(1024) void k_scan_sub(const int* __restrict__ bcnt,
                                                   int* __restrict__ bbase, int n,
                                                   int* __restrict__ rowstart, int N, int NE,
                                                   float* __restrict__ cnt, int G,
                                                   float* __restrict__ outz) {
    __shared__ int sm[1024];
    int t = threadIdx.x;
    int c0 = t * 4;
    int v0 = (c0 < n) ? bcnt[c0] : 0;
    int v1 = (c0 + 1 < n) ? bcnt[c0 + 1] : 0;
    int v2 = (c0 + 2 < n) ? bcnt[c0 + 2] : 0;
    int v3 = (c0 + 3 < n) ? bcnt[c0 + 3] : 0;
    int tot = v0 + v1 + v2 + v3;
    sm[t] = tot;
    if (t < G) cnt[t] = 0.f;
    __syncthreads();
    for (int off = 1; off < 1024; off <<= 1) {
        int u = (t >= off) ? sm[t - off] : 0;
        __syncthreads();
        sm[t] += u;
        __syncthreads();
    }
    int base = sm[t] - tot;
    if (c0 < n) bbase[c0] = base;
    if (c0 + 1 < n) bbase[c0 + 1] = base + v0;
    if (c0 + 2 < n) bbase[c0 + 2] = base + v0 + v1;
    if (c0 + 3 < n) bbase[c0 + 3] = base + v0 + v1 + v2;
    if (t == 1023) {
        bbase[n] = sm[1023];
        rowstart[N] = NE;
    }
    long tot_out = (long)G * FD;
    for (long i = t * 4; i < tot_out; i += 4096)
        *(float4*)&outz[i] = (float4){0.f, 0.f, 0.f, 0.f};
}

// ---- Pass B: bucket -> csr_src + dst16 (per-edge dst, enables k_edgew) ----
__global__ __launch_bounds__(256) void k_bucket_csr(const int* __restrict__ binned,
                                                    const int* __restrict__ bcnt,
                                                    const int* __restrict__ bbase,
                                                    int* __restrict__ csr_src,
                                                    unsigned short* __restrict__ dst16,
                                                    int* __restrict__ rowstart, int N) {
    int b = blockIdx.x;
    int t = threadIdx.x;
    __shared__ int ldeg[128], lofs[128], lcur[128];
    __shared__ int lcsr[BCAP];
    if (t < 128) ldeg[t] = 0;
    __syncthreads();
    int cnt = bcnt[b];
    if (cnt > BCAP) cnt = BCAP;
    int base = bbase[b];
    const int* reg = binned + (long)b * BCAP;
    for (int i = t; i < cnt; i += 256)
        atomicAdd(&ldeg[reg[i] >> 16], 1);
    __syncthreads();
    if (t < 128) lofs[t] = ldeg[t];
    __syncthreads();
    for (int off = 1; off < 128; off <<= 1) {
        int u = (t < 128 && t >= off) ? lofs[t - off] : 0;
        __syncthreads();
        if (t < 128) lofs[t] += u;
        __syncthreads();
    }
    if (t < 128) lcur[t] = lofs[t] - ldeg[t];
    __syncthreads();
    for (int i = t; i < cnt; i += 256) {
        int v = reg[i];
        int p = atomicAdd(&lcur[v >> 16], 1);
        lcsr[p] = v;
    }
    __syncthreads();
    for (int i = t; i < cnt; i += 256) {
        int v = lcsr[i];
        csr_src[base + i] = v & 0xFFFF;
        dst16[base + i] = (unsigned short)(b * 128 + (v >> 16));
    }
    if (t < 128) {
        int d = b * 128 + t;
        if (d < N) rowstart[d] = base + lofs[t] - ldeg[t];
    }
}

// ---- per-edge softmax weights (all 4 heads), fp16, coalesced ----
// csr is dst-sorted -> ad4[dst] loads are near-sequential; as4[src] L2-hot.
__global__ __launch_bounds__(256) void k_edgew(const int* __restrict__ csr_src,
                                               const unsigned short* __restrict__ dst16,
                                               const float4* __restrict__ as4,
                                               const float4* __restrict__ ad4,
                                               __half* __restrict__ alpha, int NE) {
    int e = blockIdx.x * 256 + threadIdx.x;
    if (e >= NE) return;
    int s = csr_src[e];
    int d = dst16[e];
    float4 a = as4[s];
    float4 b = ad4[d];
    float w0 = __expf(fminf(lrelu(a.x + b.x), 30.f));
    float w1 = __expf(fminf(lrelu(a.y + b.y), 30.f));
    float w2 = __expf(fminf(lrelu(a.z + b.z), 30.f));
    float w3 = __expf(fminf(lrelu(a.w + b.w), 30.f));
    __half2* o = (__half2*)&alpha[(long)e * 4];
    o[0] = __floats2half2_rn(w0, w1);
    o[1] = __floats2half2_rn(w2, w3);
}

// ---- wave-per-node aggregation (R11 structure) with precomputed alpha ----
// lane = 4 edge-groups (rg) x 16 channel-lanes (c16, 8 ch each); weight is a
// single contiguous fp16 load (32 B per 4-edge iteration); butterfly reduce.
__global__ __launch_bounds__(256) void k_aggr(const int* __restrict__ csr_src,
                                              const int* __restrict__ rowstart,
                                              const __half* __restrict__ alpha,
                                              const float* __restrict__ as_,
                                              const float* __restrict__ ad_,
                                              const __half* __restrict__ h,
                                              const float* __restrict__ bias,
                                              const float* __restrict__ va_s,
                                              const float* __restrict__ va_d,
                                              float* __restrict__ as_n,
                                              float* __restrict__ ad_n,
                                              __half* __restrict__ out, int N) {
    __shared__ int s_all[4][CHW];
    int t = threadIdx.x;
    int wv = t >> 6, lane = t & 63;
    int n = blockIdx.x * 4 + wv;
    if (n >= N) return;
    int* s_lds = s_all[wv];
    int c16 = lane & 15, rg = lane >> 4;
    int gh = c16 >> 2;
    int cb = c16 * 8;
    int beg = rowstart[n], end = rowstart[n + 1];
    int deg = end - beg;
    float l = 0.f;
    float acc[8] = {0.f, 0.f, 0.f, 0.f, 0.f, 0.f, 0.f, 0.f};

    for (int c0 = 0; c0 < deg; c0 += CHW) {
        int cnt = deg - c0;
        if (cnt > CHW) cnt = CHW;
        for (int i = lane; i < cnt; i += 64) s_lds[i] = csr_src[beg + c0 + i];
        const __half* ap = alpha + (long)(beg + c0) * 4;
        __builtin_amdgcn_wave_barrier();  // keep compiler from reordering LDS ops
#pragma unroll 2
        for (int e = rg; e < cnt; e += 4) {
            int s = s_lds[e];
            float w = __half2float(ap[e * 4 + gh]);
            l += w;
            float4 raw = *(const float4*)&h[(long)s * FD + cb];
            const __half* hh = (const __half*)&raw;
#pragma unroll
            for (int i = 0; i < 8; ++i)
                acc[i] += __half2float(hh[i]) * w;   // v_fma_mix_f32
        }
        __builtin_amdgcn_wave_barrier();
    }
    // butterfly over the 4 edge-groups: all lanes end with full sums
    l += __shfl_xor(l, 16);
    l += __shfl_xor(l, 32);
#pragma unroll
    for (int i = 0; i < 8; ++i) {
        acc[i] += __shfl_xor(acc[i], 16);
        acc[i] += __shfl_xor(acc[i], 32);
    }
    float adn = ad_[n * HEADS + gh];
    float sl = lrelu(as_[n * HEADS + gh] + adn);
    float sw = __expf(fminf(sl, 30.f));
    float inv = 1.f / (l + sw + 1e-16f);
    float4 rawh = *(const float4*)&h[(long)n * FD + cb];
    const __half* hh = (const __half*)&rawh;
    float4 b0 = *(const float4*)&bias[cb];
    float4 b1 = *(const float4*)&bias[cb + 4];
    float bb[8] = {b0.x, b0.y, b0.z, b0.w, b1.x, b1.y, b1.z, b1.w};
    float v[8];
#pragma unroll
    for (int i = 0; i < 8; ++i) {
        float u = (acc[i] + sw * __half2float(hh[i])) * inv + bb[i];
        v[i] = u > 0.f ? u : expm1f(u);
    }
    if (rg == 0) {
        __half o8[8];
#pragma unroll
        for (int i = 0; i < 8; ++i) o8[i] = __float2half(v[i]);
        *(float4*)&out[(long)n * FD + cb] = *(float4*)o8;
    }
    if (va_s) {  // next-layer alpha halves: rg = head, dot over all 128 ch
        const float* vs = va_s + rg * FD + cb;
        const float* vd = va_d + rg * FD + cb;
        float ps = 0.f, pd = 0.f;
#pragma unroll
        for (int i = 0; i < 8; ++i) {
            ps += v[i] * vs[i];
            pd += v[i] * vd[i];
        }
        for (int off = 1; off < 16; off <<= 1) {
            ps += __shfl_xor(ps, off);
            pd += __shfl_xor(pd, off);
        }
        if (c16 == 0) {
            as_n[n * HEADS + rg] = ps;
            ad_n[n * HEADS + rg] = pd;
        }
    }
}

// ---- pooling: batch sorted -> segmented accumulate (32 nodes/block) ----
__global__ __launch_bounds__(128) void k_pool(const __half* __restrict__ x,
                                              const int* __restrict__ batch,
                                              float* __restrict__ out,
                                              float* __restrict__ cnt, int N) {
    int n0 = blockIdx.x * 32;
    if (n0 >= N) return;
    int n1 = n0 + 32;
    if (n1 > N) n1 = N;
    int ch = threadIdx.x;
    __shared__ int gb[32];
    if (ch < n1 - n0) gb[ch] = batch[n0 + ch];
    __syncthreads();
    int g = gb[0];
    float sum = 0.f, c_local = 0.f;
    for (int n = n0; n < n1; ++n) {
        int gn = gb[n - n0];
        if (gn != g) {
            atomicAdd(&out[(long)g * FD + ch], sum);
            if (ch == 0) atomicAdd(&cnt[g], c_local);
            sum = 0.f;
            c_local = 0.f;
            g = gn;
        }
        sum += __half2float(x[(long)n * FD + ch]);
        c_local += 1.f;
    }
    atomicAdd(&out[(long)g * FD + ch], sum);
    if (ch == 0) atomicAdd(&cnt[g], c_local);
}

__global__ void k_div(float* __restrict__ out, const float* __restrict__ cnt, int G) {
    int i = blockIdx.x * 256 + threadIdx.x;
    if (i >= G * FD) return;
    float c = cnt[i >> 7];
    out[i] /= (c > 1.f ? c : 1.f);
}

extern "C" void kernel_launch(void* const* d_in, const int* in_sizes, int n_in,
                              void* d_out, int out_size, void* d_ws, size_t ws_size,
                              hipStream_t stream) {
    const float* x0     = (const float*)d_in[0];
    const float* Wall   = (const float*)d_in[1];
    const float* att_s  = (const float*)d_in[2];
    const float* att_d  = (const float*)d_in[3];
    const float* biases = (const float*)d_in[4];
    const int*   ei     = (const int*)d_in[5];
    const int*   batch  = (const int*)d_in[6];
    float*       out    = (float*)d_out;

    int N  = in_sizes[0] / FD;   // 50000 (src packing relies on N < 65536)
    int NE = in_sizes[5] / 2;    // 1600000
    int G  = out_size / FD;      // 512

    int nbuck = (N + 127) >> 7;  // 391

    long nF = (long)N * FD;
    float*    wsf      = (float*)d_ws;
    float*    asA      = wsf;                        // 4N
    float*    adA      = asA + (long)N * HEADS;      // 4N
    float*    asB      = adA + (long)N * HEADS;      // 4N
    float*    adB      = asB + (long)N * HEADS;      // 4N
    float*    cnt      = adB + (long)N * HEADS;      // G
    float*    va_s     = cnt + G;                    // 3*4*FD
    float*    va_d     = va_s + 3 * HEADS * FD;      // 3*4*FD
    int*      rowstart = (int*)(va_d + 3 * HEADS * FD); // N+1
    int*      bcnt     = rowstart + N + 1;           // nbuck
    int*      bbase    = bcnt + nbuck;               // nbuck+1
    int*      csr_src  = bbase + nbuck + 1;          // NE
    unsigned short* dst16 = (unsigned short*)(csr_src + NE);  // NE ushorts
    __half*   h        = (__half*)(dst16 + ((NE + 1) & ~1));  // nF halves
    __half*   x16      = h + nF;                     // nF halves
    _Float16* W16T     = (_Float16*)(x16 + nF);      // 3*FD*FD halves
    __half*   alpha    = (__half*)(W16T + 3 * FD * FD); // NE*4 halves
    int*      binned   = (int*)(alpha + (long)NE * 4);  // nbuck*BCAP ints

    int ncvt = (int)((nF / 4 + 255) / 256);

    // ---- prep (cvt + W prep + bcnt zero) + CSR build ----
    k_prep<<<ncvt + 4, 256, 0, stream>>>(x0, x16, nF, Wall, att_s, att_d,
                                         W16T, va_s, va_d, bcnt, nbuck, ncvt);
    k_bin<<<(NE + CH - 1) / CH, 1024, 0, stream>>>(ei, NE, nbuck, bcnt, binned);
    k_scan_sub<<<1, 1024, 0, stream>>>(bcnt, bbase, nbuck, rowstart, N, NE, cnt, G, out);
    k_bucket_csr<<<nbuck, 256, 0, stream>>>(binned, bcnt, bbase, csr_src, dst16, rowstart, N);

    // ---- layers (alpha for layer 0 standalone; layers 1,2 from aggr epilogue) ----
    float* asR[3] = {asA, asB, asA};
    float* adR[3] = {adA, adB, adA};
    for (int l = 0; l < 3; ++l) {
        k_gemm_mfma<<<(N + 127) / 128, 256, 0, stream>>>(x16, W16T + (long)l * FD * FD, h, N);
        if (l == 0)
            k_alpha<<<(N + 15) / 16, 256, 0, stream>>>(h, att_s, att_d, asA, adA, N);
        k_edgew<<<(NE + 255) / 256, 256, 0, stream>>>(csr_src, dst16,
                                                      (const float4*)asR[l],
                                                      (const float4*)adR[l], alpha, NE);
        const float* vs = (l < 2) ? va_s + (long)(l + 1) * HEADS * FD : nullptr;
        const float* vd = (l < 2) ? va_d + (long)(l + 1) * HEADS * FD : nullptr;
        k_aggr<<<(N + 3) / 4, 256, 0, stream>>>(csr_src, rowstart, alpha, asR[l], adR[l], h,
                                                biases + l * FD, vs, vd,
                                                asR[l + 1 < 3 ? l + 1 : 0],
                                                adR[l + 1 < 3 ? l + 1 : 0], x16, N);
    }

    // ---- pooling ----
    k_pool<<<(N + 31) / 32, 128, 0, stream>>>(x16, batch, out, cnt, N);
    k_div<<<(G * FD + 255) / 256, 256, 0, stream>>>(out, cnt, G);
}

// Round 15
// 357.866 us; speedup vs baseline: 1.1941x; 1.0914x over previous
//
#include <hip/hip_runtime.h>
#include <hip/hip_fp16.h>
#include <math.h>

#define HEADS 4
#define HDIM 32
#define FD 128
#define NEG 0.2f
#define BCAP 4608    // per bucket (128 dsts) capacity (lambda=4092, +8 sigma)
#define CH 8192      // edges per binning chunk
#define CHW 128      // edges per aggr chunk (per wave)

typedef _Float16 f16x8 __attribute__((ext_vector_type(8)));
typedef float f32x4 __attribute__((ext_vector_type(4)));

__device__ __forceinline__ float lrelu(float x) { return fmaxf(x, NEG * x); }

// ---- fused prep: x0 cvt (blocks 0..ncvt-1), W16T+va (ncvt..ncvt+2),
//      bcnt zero (ncvt+3) ----
__global__ __launch_bounds__(256) void k_prep(const float* __restrict__ x,
                                              __half* __restrict__ o, long nF,
                                              const float* __restrict__ W,
                                              const float* __restrict__ att_s,
                                              const float* __restrict__ att_d,
                                              _Float16* __restrict__ W16T,
                                              float* __restrict__ va_s,
                                              float* __restrict__ va_d,
                                              int* __restrict__ bcnt, int nbuck,
                                              int ncvt) {
    int b = blockIdx.x;
    if (b < ncvt) {
        long i = ((long)b * 256 + threadIdx.x) * 4;
        if (i < nF) {
            float4 v = *(const float4*)&x[i];
            *(__half2*)&o[i] = __floats2half2_rn(v.x, v.y);
            *(__half2*)&o[i + 2] = __floats2half2_rn(v.z, v.w);
        }
        return;
    }
    if (b == ncvt + 3) {
        for (int i = threadIdx.x; i < nbuck; i += 256) bcnt[i] = 0;
        return;
    }
    int l = b - ncvt;
    const float* Wl = W + (long)l * FD * FD;
    _Float16* ow = W16T + (long)l * FD * FD;
    for (int i = threadIdx.x; i < FD * FD; i += 256) {
        int k = i >> 7, n = i & 127;
        ow[n * FD + k] = (_Float16)Wl[i];
    }
    const float* as_l = att_s + l * HEADS * HDIM;
    const float* ad_l = att_d + l * HEADS * HDIM;
    for (int idx = threadIdx.x; idx < HEADS * FD; idx += 256) {
        int hd = idx >> 7, k = idx & 127;
        float ss = 0.f, dd = 0.f;
        for (int c = 0; c < HDIM; ++c) {
            float w = Wl[k * FD + hd * HDIM + c];
            ss += w * as_l[hd * HDIM + c];
            dd += w * ad_l[hd * HDIM + c];
        }
        va_s[(long)l * HEADS * FD + idx] = ss;
        va_d[(long)l * HEADS * FD + idx] = dd;
    }
}

// ---- MFMA GEMM: h = x16 @ W (fp16 in, fp16 out, fp32 accum) ----
__global__ __launch_bounds__(256) void k_gemm_mfma(const __half* __restrict__ x16,
                                                   const _Float16* __restrict__ W16T,
                                                   __half* __restrict__ h, int N) {
    __shared__ _Float16 wl[FD * FD];  // 32 KB, [n][k]
    int t = threadIdx.x;
    for (int i = t * 8; i < FD * FD; i += 2048)
        *(f16x8*)&wl[i] = *(const f16x8*)&W16T[i];

    int w = t >> 6, lane = t & 63;
    int m = lane & 15, quad = lane >> 4;
    int row0 = blockIdx.x * 128 + w * 32;

    f16x8 a[2][4];
    f16x8 zf = {};
#pragma unroll
    for (int rt = 0; rt < 2; ++rt) {
        int gr = row0 + rt * 16 + m;
#pragma unroll
        for (int kc = 0; kc < 4; ++kc)
            a[rt][kc] = (gr < N) ? *(const f16x8*)&x16[(long)gr * FD + kc * 32 + quad * 8] : zf;
    }
    f32x4 acc[2][8];
#pragma unroll
    for (int rt = 0; rt < 2; ++rt)
#pragma unroll
        for (int c = 0; c < 8; ++c) acc[rt][c] = (f32x4){0.f, 0.f, 0.f, 0.f};

    __syncthreads();
#pragma unroll
    for (int c = 0; c < 8; ++c) {
        int nb = c * 16 + m;
#pragma unroll
        for (int kc = 0; kc < 4; ++kc) {
            f16x8 b = *(f16x8*)&wl[nb * FD + kc * 32 + quad * 8];
            acc[0][c] = __builtin_amdgcn_mfma_f32_16x16x32_f16(a[0][kc], b, acc[0][c], 0, 0, 0);
            acc[1][c] = __builtin_amdgcn_mfma_f32_16x16x32_f16(a[1][kc], b, acc[1][c], 0, 0, 0);
        }
    }
#pragma unroll
    for (int rt = 0; rt < 2; ++rt) {
        int rbase = row0 + rt * 16 + quad * 4;
#pragma unroll
        for (int c = 0; c < 8; ++c) {
            int col = c * 16 + m;
#pragma unroll
            for (int i = 0; i < 4; ++i) {
                int gr = rbase + i;
                if (gr < N) h[(long)gr * FD + col] = __float2half(acc[rt][c][i]);
            }
        }
    }
}

// ---- attention halves for layer 0 (from h): 16 threads/node ----
__global__ __launch_bounds__(256) void k_alpha(const __half* __restrict__ h,
                                               const float* __restrict__ a_s,
                                               const float* __restrict__ a_d,
                                               float* __restrict__ as_o,
                                               float* __restrict__ ad_o, int N) {
    int t = threadIdx.x;
    int n = blockIdx.x * 16 + (t >> 4);
    if (n >= N) return;
    int c16 = t & 15, gh = c16 >> 2, cb = c16 * 8;
    int c32 = (c16 & 3) * 8;
    float4 raw = *(const float4*)&h[(long)n * FD + cb];
    const __half* hh = (const __half*)&raw;
    float vs = 0.f, vd = 0.f;
#pragma unroll
    for (int i = 0; i < 8; ++i) {
        float hv = __half2float(hh[i]);
        vs += hv * a_s[gh * HDIM + c32 + i];
        vd += hv * a_d[gh * HDIM + c32 + i];
    }
    vs += __shfl_xor(vs, 1); vs += __shfl_xor(vs, 2);
    vd += __shfl_xor(vd, 1); vd += __shfl_xor(vd, 2);
    if ((c16 & 3) == 0) {
        as_o[n * HEADS + gh] = vs;
        ad_o[n * HEADS + gh] = vd;
    }
}

// ---- Pass A: chunk-reserved binning ----
__global__ __launch_bounds__(1024) void k_bin(const int* __restrict__ ei, int NE,
                                              int nbuck,
                                              int* __restrict__ bcnt,
                                              int* __restrict__ binned) {
    __shared__ int hist[512];
    __shared__ int gbase[512];
    int t = threadIdx.x;
    int c0 = blockIdx.x * CH;
    if (t < 512) hist[t] = 0;
    __syncthreads();
    int sub[8], val[8], loff[8];
#pragma unroll
    for (int k = 0; k < 8; ++k) {
        int idx = c0 + k * 1024 + t;
        sub[k] = -1;
        if (idx < NE) {
            int s = ei[idx], d = ei[NE + idx];
            sub[k] = d >> 7;
            val[k] = s | ((d & 127) << 16);   // requires N < 65536
            loff[k] = atomicAdd(&hist[sub[k]], 1);
        }
    }
    __syncthreads();
    if (t < 512 && t < nbuck && hist[t] > 0)
        gbase[t] = atomicAdd(&bcnt[t], hist[t]);
    __syncthreads();
#pragma unroll
    for (int k = 0; k < 8; ++k) {
        if (sub[k] >= 0) {
            int p = gbase[sub[k]] + loff[k];
            if (p < BCAP) binned[(long)sub[k] * BCAP + p] = val[k];
        }
    }
}

// scan of bcnt -> bbase; also rowstart[N]=NE, cnt[0..G)=0, out zeroing
__global__ __launch_bounds__(1024) void k_scan_sub(const int* __restrict__ bcnt,
                                                   int* __restrict__ bbase, int n,
                                                   int* __restrict__ rowstart, int N, int NE,
                                                   float* __restrict__ cnt, int G,
                                                   float* __restrict__ outz) {
    __shared__ int sm[1024];
    int t = threadIdx.x;
    int c0 = t * 4;
    int v0 = (c0 < n) ? bcnt[c0] : 0;
    int v1 = (c0 + 1 < n) ? bcnt[c0 + 1] : 0;
    int v2 = (c0 + 2 < n) ? bcnt[c0 + 2] : 0;
    int v3 = (c0 + 3 < n) ? bcnt[c0 + 3] : 0;
    int tot = v0 + v1 + v2 + v3;
    sm[t] = tot;
    if (t < G) cnt[t] = 0.f;
    __syncthreads();
    for (int off = 1; off < 1024; off <<= 1) {
        int u = (t >= off) ? sm[t - off] : 0;
        __syncthreads();
        sm[t] += u;
        __syncthreads();
    }
    int base = sm[t] - tot;
    if (c0 < n) bbase[c0] = base;
    if (c0 + 1 < n) bbase[c0 + 1] = base + v0;
    if (c0 + 2 < n) bbase[c0 + 2] = base + v0 + v1;
    if (c0 + 3 < n) bbase[c0 + 3] = base + v0 + v1 + v2;
    if (t == 1023) {
        bbase[n] = sm[1023];
        rowstart[N] = NE;
    }
    long tot_out = (long)G * FD;
    for (long i = t * 4; i < tot_out; i += 4096)
        *(float4*)&outz[i] = (float4){0.f, 0.f, 0.f, 0.f};
}

__global__ __launch_bounds__(256) void k_bucket_csr(const int* __restrict__ binned,
                                                    const int* __restrict__ bcnt,
                                                    const int* __restrict__ bbase,
                                                    int* __restrict__ csr_src,
                                                    int* __restrict__ rowstart, int N) {
    int b = blockIdx.x;
    int t = threadIdx.x;
    __shared__ int ldeg[128], lofs[128], lcur[128];
    __shared__ int lcsr[BCAP];
    if (t < 128) ldeg[t] = 0;
    __syncthreads();
    int cnt = bcnt[b];
    if (cnt > BCAP) cnt = BCAP;
    int base = bbase[b];
    const int* reg = binned + (long)b * BCAP;
    for (int i = t; i < cnt; i += 256)
        atomicAdd(&ldeg[reg[i] >> 16], 1);
    __syncthreads();
    if (t < 128) lofs[t] = ldeg[t];
    __syncthreads();
    for (int off = 1; off < 128; off <<= 1) {
        int u = (t < 128 && t >= off) ? lofs[t - off] : 0;
        __syncthreads();
        if (t < 128) lofs[t] += u;
        __syncthreads();
    }
    if (t < 128) lcur[t] = lofs[t] - ldeg[t];
    __syncthreads();
    for (int i = t; i < cnt; i += 256) {
        int v = reg[i];
        int p = atomicAdd(&lcur[v >> 16], 1);
        lcsr[p] = v & 0xFFFF;
    }
    __syncthreads();
    for (int i = t; i < cnt; i += 256) csr_src[base + i] = lcsr[i];
    if (t < 128) {
        int d = b * 128 + t;
        if (d < N) rowstart[d] = base + lofs[t] - ldeg[t];
    }
}

// ---- wave-per-node aggregation (R11 structure, inline weights) ----
// lane = 4 edge-groups (rg) x 16 channel-lanes (c16, 8 ch each); weights
// computed inline (4-way redundant per head); s_lds holds src*4 so both the
// as_ index (s4+gh) and h byte-row (s4<<5) derive cheaply. ELU via
// __expf(u)-1 (abs err ~1e-7 for u<=0) instead of the multi-instr expm1f.
__global__ __launch_bounds__(256) void k_aggr(const int* __restrict__ csr_src,
                                              const int* __restrict__ rowstart,
                                              const float* __restrict__ as_,
                                              const float* __restrict__ ad_,
                                              const __half* __restrict__ h,
                                              const float* __restrict__ bias,
                                              const float* __restrict__ va_s,
                                              const float* __restrict__ va_d,
                                              float* __restrict__ as_n,
                                              float* __restrict__ ad_n,
                                              __half* __restrict__ out, int N) {
    __shared__ int s_all[4][CHW];
    int t = threadIdx.x;
    int wv = t >> 6, lane = t & 63;
    int n = blockIdx.x * 4 + wv;
    if (n >= N) return;
    int* s_lds = s_all[wv];
    int c16 = lane & 15, rg = lane >> 4;
    int gh = c16 >> 2;
    int cb = c16 * 8;
    int beg = rowstart[n], end = rowstart[n + 1];
    int deg = end - beg;
    float adn = ad_[n * HEADS + gh];
    float l = 0.f;
    float acc[8] = {0.f, 0.f, 0.f, 0.f, 0.f, 0.f, 0.f, 0.f};

    for (int c0 = 0; c0 < deg; c0 += CHW) {
        int cnt = deg - c0;
        if (cnt > CHW) cnt = CHW;
        for (int i = lane; i < cnt; i += 64) s_lds[i] = csr_src[beg + c0 + i] << 2;
        __builtin_amdgcn_wave_barrier();  // keep compiler from reordering LDS ops
#pragma unroll 2
        for (int e = rg; e < cnt; e += 4) {
            int s4 = s_lds[e];
            float lg = lrelu(as_[s4 + gh] + adn);
            float w = __expf(fminf(lg, 30.f));
            l += w;
            float4 raw = *(const float4*)&h[((long)s4 << 5) + cb];
            const __half* hh = (const __half*)&raw;
#pragma unroll
            for (int i = 0; i < 8; ++i)
                acc[i] += __half2float(hh[i]) * w;   // v_fma_mix_f32
        }
        __builtin_amdgcn_wave_barrier();
    }
    // butterfly over the 4 edge-groups: all lanes end with full sums
    l += __shfl_xor(l, 16);
    l += __shfl_xor(l, 32);
#pragma unroll
    for (int i = 0; i < 8; ++i) {
        acc[i] += __shfl_xor(acc[i], 16);
        acc[i] += __shfl_xor(acc[i], 32);
    }
    float sl = lrelu(as_[n * HEADS + gh] + adn);
    float sw = __expf(fminf(sl, 30.f));
    float inv = 1.f / (l + sw + 1e-16f);
    float4 rawh = *(const float4*)&h[(long)n * FD + cb];
    const __half* hh = (const __half*)&rawh;
    float4 b0 = *(const float4*)&bias[cb];
    float4 b1 = *(const float4*)&bias[cb + 4];
    float bb[8] = {b0.x, b0.y, b0.z, b0.w, b1.x, b1.y, b1.z, b1.w};
    float v[8];
#pragma unroll
    for (int i = 0; i < 8; ++i) {
        float u = (acc[i] + sw * __half2float(hh[i])) * inv + bb[i];
        v[i] = u > 0.f ? u : __expf(u) - 1.f;   // ELU; err ~1e-7 vs expm1f
    }
    if (rg == 0) {
        __half o8[8];
#pragma unroll
        for (int i = 0; i < 8; ++i) o8[i] = __float2half(v[i]);
        *(float4*)&out[(long)n * FD + cb] = *(float4*)o8;
    }
    if (va_s) {  // next-layer alpha halves: rg = head, dot over all 128 ch
        const float* vs = va_s + rg * FD + cb;
        const float* vd = va_d + rg * FD + cb;
        float ps = 0.f, pd = 0.f;
#pragma unroll
        for (int i = 0; i < 8; ++i) {
            ps += v[i] * vs[i];
            pd += v[i] * vd[i];
        }
        for (int off = 1; off < 16; off <<= 1) {
            ps += __shfl_xor(ps, off);
            pd += __shfl_xor(pd, off);
        }
        if (c16 == 0) {
            as_n[n * HEADS + rg] = ps;
            ad_n[n * HEADS + rg] = pd;
        }
    }
}

// ---- pooling: batch sorted -> segmented accumulate (32 nodes/block) ----
__global__ __launch_bounds__(128) void k_pool(const __half* __restrict__ x,
                                              const int* __restrict__ batch,
                                              float* __restrict__ out,
                                              float* __restrict__ cnt, int N) {
    int n0 = blockIdx.x * 32;
    if (n0 >= N) return;
    int n1 = n0 + 32;
    if (n1 > N) n1 = N;
    int ch = threadIdx.x;
    __shared__ int gb[32];
    if (ch < n1 - n0) gb[ch] = batch[n0 + ch];
    __syncthreads();
    int g = gb[0];
    float sum = 0.f, c_local = 0.f;
    for (int n = n0; n < n1; ++n) {
        int gn = gb[n - n0];
        if (gn != g) {
            atomicAdd(&out[(long)g * FD + ch], sum);
            if (ch == 0) atomicAdd(&cnt[g], c_local);
            sum = 0.f;
            c_local = 0.f;
            g = gn;
        }
        sum += __half2float(x[(long)n * FD + ch]);
        c_local += 1.f;
    }
    atomicAdd(&out[(long)g * FD + ch], sum);
    if (ch == 0) atomicAdd(&cnt[g], c_local);
}

__global__ void k_div(float* __restrict__ out, const float* __restrict__ cnt, int G) {
    int i = blockIdx.x * 256 + threadIdx.x;
    if (i >= G * FD) return;
    float c = cnt[i >> 7];
    out[i] /= (c > 1.f ? c : 1.f);
}

extern "C" void kernel_launch(void* const* d_in, const int* in_sizes, int n_in,
                              void* d_out, int out_size, void* d_ws, size_t ws_size,
                              hipStream_t stream) {
    const float* x0     = (const float*)d_in[0];
    const float* Wall   = (const float*)d_in[1];
    const float* att_s  = (const float*)d_in[2];
    const float* att_d  = (const float*)d_in[3];
    const float* biases = (const float*)d_in[4];
    const int*   ei     = (const int*)d_in[5];
    const int*   batch  = (const int*)d_in[6];
    float*       out    = (float*)d_out;

    int N  = in_sizes[0] / FD;   // 50000 (src packing relies on N < 65536)
    int NE = in_sizes[5] / 2;    // 1600000
    int G  = out_size / FD;      // 512

    int nbuck = (N + 127) >> 7;  // 391

    long nF = (long)N * FD;
    float*    wsf      = (float*)d_ws;
    float*    asA      = wsf;                        // 4N
    float*    adA      = asA + (long)N * HEADS;      // 4N
    float*    asB      = adA + (long)N * HEADS;      // 4N
    float*    adB      = asB + (long)N * HEADS;      // 4N
    float*    cnt      = adB + (long)N * HEADS;      // G
    float*    va_s     = cnt + G;                    // 3*4*FD
    float*    va_d     = va_s + 3 * HEADS * FD;      // 3*4*FD
    int*      rowstart = (int*)(va_d + 3 * HEADS * FD); // N+1
    int*      bcnt     = rowstart + N + 1;           // nbuck
    int*      bbase    = bcnt + nbuck;               // nbuck+1
    int*      csr_src  = bbase + nbuck + 1;          // NE
    __half*   h        = (__half*)(csr_src + NE);    // nF halves
    __half*   x16      = h + nF;                     // nF halves
    _Float16* W16T     = (_Float16*)(x16 + nF);      // 3*FD*FD halves
    int*      binned   = (int*)(W16T + 3 * FD * FD); // nbuck*BCAP ints

    int ncvt = (int)((nF / 4 + 255) / 256);

    // ---- prep (cvt + W prep + bcnt zero) + CSR build ----
    k_prep<<<ncvt + 4, 256, 0, stream>>>(x0, x16, nF, Wall, att_s, att_d,
                                         W16T, va_s, va_d, bcnt, nbuck, ncvt);
    k_bin<<<(NE + CH - 1) / CH, 1024, 0, stream>>>(ei, NE, nbuck, bcnt, binned);
    k_scan_sub<<<1, 1024, 0, stream>>>(bcnt, bbase, nbuck, rowstart, N, NE, cnt, G, out);
    k_bucket_csr<<<nbuck, 256, 0, stream>>>(binned, bcnt, bbase, csr_src, rowstart, N);

    // ---- layers (alpha for layer 0 standalone; layers 1,2 from aggr epilogue) ----
    float* asR[3] = {asA, asB, asA};
    float* adR[3] = {adA, adB, adA};
    for (int l = 0; l < 3; ++l) {
        k_gemm_mfma<<<(N + 127) / 128, 256, 0, stream>>>(x16, W16T + (long)l * FD * FD, h, N);
        if (l == 0)
            k_alpha<<<(N + 15) / 16, 256, 0, stream>>>(h, att_s, att_d, asA, adA, N);
        const float* vs = (l < 2) ? va_s + (long)(l + 1) * HEADS * FD : nullptr;
        const float* vd = (l < 2) ? va_d + (long)(l + 1) * HEADS * FD : nullptr;
        k_aggr<<<(N + 3) / 4, 256, 0, stream>>>(csr_src, rowstart, asR[l], adR[l], h,
                                                biases + l * FD, vs, vd,
                                                asR[l + 1 < 3 ? l + 1 : 0],
                                                adR[l + 1 < 3 ? l + 1 : 0], x16, N);
    }

    // ---- pooling ----
    k_pool<<<(N + 31) / 32, 128, 0, stream>>>(x16, batch, out, cnt, N);
    k_div<<<(G * FD + 255) / 256, 256, 0, stream>>>(out, cnt, G);
}